// Round 16
// baseline (1044.074 us; speedup 1.0000x reference)
//
#include <hip/hip_runtime.h>
#include <hip/hip_bf16.h>
#include <math.h>

#define B_ 16
#define L_ 4096
#define H_ 8
#define D_ 64
#define S_ 45          // sample_k = 5*ceil(ln(4096)) = 45
#define U_ 45          // n_top = 45
#define BH_ (B_*H_)
#define NC_ 8          // k-chunks per (b,h) in attention kernel
#define CK_ (L_/NC_)   // 512 keys per chunk

// ---- ws layout (float offsets) ----
#define OFF_MEAN 0                      // 8192
#define OFF_MP   (OFF_MEAN + BH_*D_)    // 16*8192 = 131072
#define OFF_M    (OFF_MP + 16*BH_*D_)   // 524288
#define OFF_TOPQ (OFF_M + BH_*L_)       // 5760 ints
#define OFF_PL   (OFF_TOPQ + BH_*U_ + 32)
#define OFF_PCTX (OFF_PL + BH_*NC_*U_)  // BH_*NC_*U_*D_ floats

// ---------------- mean over L of V, stage 1: per-chunk partials ----------------
__global__ void mean_kernel(const float* __restrict__ V, float* __restrict__ mp) {
    int bid = blockIdx.x;             // BH_*16
    int bh = bid >> 4, chunk = bid & 15;
    int b = bh >> 3, h = bh & 7;
    int t = threadIdx.x;              // 256
    int d = t & 63, r0 = t >> 6;      // 0..3
    float sum = 0.f;
    int base = ((b*L_ + chunk*256)*H_ + h)*D_ + d;
    for (int r = r0; r < 256; r += 4)
        sum += V[base + r*(H_*D_)];
    __shared__ float sm[256];
    sm[t] = sum; __syncthreads();
    if (t < 64) {
        float s = sm[t] + sm[t+64] + sm[t+128] + sm[t+192];
        mp[chunk*(BH_*D_) + bh*D_ + t] = s;
    }
}

// ---------------- mean stage 2 ----------------
__global__ void meanfin_kernel(const float* __restrict__ mp, float* __restrict__ mean) {
    int i = blockIdx.x*256 + threadIdx.x;   // 8192 total -> 32 blocks
    float s = 0.f;
    for (int c = 0; c < 16; ++c) s += mp[c*(BH_*D_) + i];
    mean[i] = s * (1.0f/L_);
}

// ---------------- broadcast mean into output ----------------
__global__ void fill_kernel(const float* __restrict__ mean, float4* __restrict__ out4) {
    int total = B_*L_*H_*D_/4;  // 8388608
    for (int i = blockIdx.x*blockDim.x + threadIdx.x; i < total; i += gridDim.x*blockDim.x) {
        int e = i << 2;
        int d = e & 63;
        int h = (e >> 6) & 7;
        int b = e >> 21;            // L_*H_*D_ = 2^21
        out4[i] = *(const float4*)&mean[((b<<3)+h)*D_ + d];
    }
}

// DPP-based 16-lane sum reduce: xor1, xor2 (quad_perm), half-mirror, mirror.
__device__ __forceinline__ float dpp_add16(float x) {
    int xi, yi;
    xi = __float_as_int(x);
    yi = __builtin_amdgcn_update_dpp(0, xi, 0xB1, 0xf, 0xf, true);  // quad_perm [1,0,3,2]
    x += __int_as_float(yi);
    xi = __float_as_int(x);
    yi = __builtin_amdgcn_update_dpp(0, xi, 0x4E, 0xf, 0xf, true);  // quad_perm [2,3,0,1]
    x += __int_as_float(yi);
    xi = __float_as_int(x);
    yi = __builtin_amdgcn_update_dpp(0, xi, 0x141, 0xf, 0xf, true); // row_half_mirror (^7)
    x += __int_as_float(yi);
    xi = __float_as_int(x);
    yi = __builtin_amdgcn_update_dpp(0, xi, 0x140, 0xf, 0xf, true); // row_mirror (^15)
    x += __int_as_float(yi);
    return x;
}

// 8-lane sum reduce: xor1, xor2, half-mirror (first 3 stages of dpp_add16).
// All 8 lanes of the group end with the full 8-lane sum.
__device__ __forceinline__ float dpp_add8(float x) {
    int xi, yi;
    xi = __float_as_int(x);
    yi = __builtin_amdgcn_update_dpp(0, xi, 0xB1, 0xf, 0xf, true);  // quad_perm [1,0,3,2]
    x += __int_as_float(yi);
    xi = __float_as_int(x);
    yi = __builtin_amdgcn_update_dpp(0, xi, 0x4E, 0xf, 0xf, true);  // quad_perm [2,3,0,1]
    x += __int_as_float(yi);
    xi = __float_as_int(x);
    yi = __builtin_amdgcn_update_dpp(0, xi, 0x141, 0xf, 0xf, true); // row_half_mirror (^7)
    x += __int_as_float(yi);
    return x;
}

// 8-float dot vs (qa,qb), 8-lane reduce, accumulate max/sum
#define MRED8(ka, kb) { \
    float p0_ = qa.x*(ka).x + qa.y*(ka).y + qa.z*(ka).z + qa.w*(ka).w; \
    float p1_ = qb.x*(kb).x + qb.y*(kb).y + qb.z*(kb).z + qb.w*(kb).w; \
    float p_ = dpp_add8(p0_ + p1_); \
    maxv = fmaxf(maxv, p_); sumv += p_; }

// ---------------- M = max_s(QK_s) - sum_s(QK_s)/L_K ----------------
// Grid 1024 x 256, plain launch_bounds(256): 4 blocks/CU grid-capped, whole
// grid resident, single lockstep K sweep. Slab = (b, single head): 2MB < L2.
// NEW: 8-LANE groups -- lane covers 8 floats (2x float4, +16B fold) of the
// K row. 8 q's per wave (vs 4): reduce is 3 DPP stages serving 8 q's ->
// per-q-sample VALU ~2x lower; 8 float4 loads in flight per batch (2x MLP).
// ALLOCATOR LEDGER (do not touch): min-waves launch_bounds ALWAYS collapses
// VGPR below need and spills GBs (rounds 5,7,13). Tripwire: VGPR>128 or
// WRITE_SIZE >> 10MB -> revert to round-15 m_kernel.
__global__ __launch_bounds__(256) void m_kernel(const float* __restrict__ Q,
                                                const float* __restrict__ K,
                                                const int* __restrict__ idx,
                                                float* __restrict__ M) {
    int bid = blockIdx.x;              // 1024
    int xcd  = bid & 7;
    int slot = bid >> 3;               // 0..127
    int q0 = slot*32;
    int t = threadIdx.x;
    int wave = t >> 6, lane = t & 63;

    __shared__ int silds[32*48];       // 6 KB, padded stride 48
    for (int g = t; g < 32*48; g += 256) {
        int u = g / 48, s = g - u*48;
        if (s < S_) silds[g] = idx[(q0+u)*S_ + s];
    }
    __syncthreads();

    int grp = lane >> 3;               // 0..7
    int d8 = (lane & 7) * 8;
    int myq = wave*8 + grp;            // 0..31
    int q = q0 + myq;
    const int* myidx = &silds[myq*48];

    for (int si = 0; si < 16; ++si) {
        int slab = xcd*16 + si;        // == bh, 0..127
        int b = slab >> 3, h = slab & 7;
        const float* Kb = K + b*(L_*H_*D_) + h*D_;   // + k*512 + d8
        const float* qp = &Q[(b*L_ + q)*(H_*D_) + h*D_ + d8];
        float4 qa = *(const float4*)qp;
        float4 qb = *(const float4*)(qp + 4);
        float maxv = -3.0e38f, sumv = 0.f;
        #pragma unroll 2
        for (int c = 0; c < 11; ++c) {             // 11*4 = 44 samples
            int4 k4 = *(const int4*)&myidx[c*4];
            const float* r0 = Kb + k4.x*(H_*D_) + d8;
            const float* r1 = Kb + k4.y*(H_*D_) + d8;
            const float* r2 = Kb + k4.z*(H_*D_) + d8;
            const float* r3 = Kb + k4.w*(H_*D_) + d8;
            float4 a0 = *(const float4*)r0, a1 = *(const float4*)(r0 + 4);
            float4 b0 = *(const float4*)r1, b1 = *(const float4*)(r1 + 4);
            float4 c0 = *(const float4*)r2, c1 = *(const float4*)(r2 + 4);
            float4 e0 = *(const float4*)r3, e1 = *(const float4*)(r3 + 4);
            MRED8(a0, a1); MRED8(b0, b1); MRED8(c0, c1); MRED8(e0, e1);
        }
        {   // sample 44
            int k = myidx[44];
            const float* r = Kb + k*(H_*D_) + d8;
            float4 a0 = *(const float4*)r, a1 = *(const float4*)(r + 4);
            MRED8(a0, a1);
        }
        if ((lane & 7) == 0)
            M[slab*L_ + q] = maxv - sumv * (1.0f/L_);
    }
}

// ---------------- top-45 per (b,h): one wave per bh, all in registers ----------------
__global__ __launch_bounds__(256) void topk_kernel(const float* __restrict__ M,
                                                   int* __restrict__ topq) {
    int wave = threadIdx.x >> 6, lane = threadIdx.x & 63;
    int bh = blockIdx.x*4 + wave;      // 32 blocks
    const float* Mr = M + bh*L_;
    float v[64];
    #pragma unroll
    for (int j = 0; j < 64; ++j) v[j] = Mr[j*64 + lane];
    for (int it = 0; it < U_; ++it) {
        float lm = v[0]; int lj = 0;
        #pragma unroll
        for (int j = 1; j < 64; ++j) {
            bool g = v[j] > lm;
            lm = g ? v[j] : lm;
            lj = g ? j : lj;
        }
        float bm = lm; int bi = lj*64 + lane;
        #pragma unroll
        for (int off = 1; off < 64; off <<= 1) {
            float om = __shfl_xor(bm, off);
            int   oi = __shfl_xor(bi, off);
            if (om > bm || (om == bm && oi < bi)) { bm = om; bi = oi; }
        }
        if (lane == 0) topq[bh*U_ + it] = bi;
        int wl = bi & 63, wj = bi >> 6;
        if (lane == wl) {
            #pragma unroll
            for (int j = 0; j < 64; ++j)
                if (j == wj) v[j] = -3.0e38f;
        }
    }
}

// ---------------- attention over top-45 q's, exp-direct (no online softmax) ----------------
// Unnormalized: pl = sum_k e^(s_k), pctx = sum_k e^(s_k) V[k].  exp(s) is safe:
// |s| <= |q||k|/8 << 88 for this data, so no overflow; softmax ratio is identical.
// K staging deleted (K chunk read exactly once -> global->LDS was overhead);
// kreg[8] (two D-halves) loads straight from global; waves fully independent
// after the qidx_s barrier (wlds rows wave-partitioned) -> they drift/overlap.
// Q rows via wave-uniform scalar loads (SGPR). Phase B = round-8 vreg[64] form
// (4x16 chunking spilled 3.5GB in round 9 -- do not chunk).
__global__ __launch_bounds__(256, 2) void attn_kernel(
        const float* __restrict__ Q, const float* __restrict__ K, const float* __restrict__ V,
        const int* __restrict__ topq,
        float* __restrict__ pl, float* __restrict__ pctx) {
    int bid = blockIdx.x;              // BH_*NC_
    int bh = bid / NC_, c = bid % NC_;
    int b = bh >> 3, h = bh & 7;
    int t = threadIdx.x, wave = t >> 6, lane = t & 63;

    __shared__ int   qidx_s[U_];
    __shared__ float wlds[48*64];      // 12 KB

    if (t < U_) qidx_s[t] = topq[bh*U_ + t];
    __syncthreads();

    float lpart[12], ctx_u[12];
    #pragma unroll
    for (int j = 0; j < 12; ++j) { lpart[j] = 0.f; ctx_u[j] = 0.f; }

    int k0base = c*CK_;
    for (int sc = 0; sc < CK_/64; ++sc) {      // 8 sub-chunks of 64 keys
        int k0 = k0base + sc*64;
        const float* Krow = K + ((size_t)(b*L_ + k0 + lane)*H_ + h)*D_;

        // phase A: lane = k. kreg direct from global, two D-halves; dots in dotu.
        float dotu[12];
        #pragma unroll
        for (int j = 0; j < 12; ++j) dotu[j] = 0.f;
        #pragma unroll
        for (int dh = 0; dh < 2; ++dh) {
            float4 kreg[8];
            #pragma unroll
            for (int cc = 0; cc < 8; ++cc)
                kreg[cc] = *(const float4*)&Krow[dh*32 + cc*4];
            #pragma unroll
            for (int j = 0; j < 12; ++j) {
                int u = wave + 4*j;
                if (u >= U_) break;
                int qrow = __builtin_amdgcn_readfirstlane(qidx_s[u]);
                const float* qp = Q + ((size_t)(b*L_ + qrow)*H_ + h)*D_ + dh*32;
                float d0 = 0.f, d1 = 0.f, d2 = 0.f, d3 = 0.f;
                #pragma unroll
                for (int cc = 0; cc < 8; ++cc) {
                    float4 kv = kreg[cc];
                    d0 += qp[cc*4+0]*kv.x; d1 += qp[cc*4+1]*kv.y;
                    d2 += qp[cc*4+2]*kv.z; d3 += qp[cc*4+3]*kv.w;
                }
                dotu[j] += (d0+d1)+(d2+d3);
            }
        }
        #pragma unroll
        for (int j = 0; j < 12; ++j) {
            int u = wave + 4*j;
            if (u >= U_) break;
            float e = __expf(dotu[j] * 0.125f);   // 1/sqrt(64)
            lpart[j] += e;
            wlds[u*64 + lane] = e;
        }
        // no barrier: each wave reads back only the wlds rows it wrote.

        // phase B: lane = d. V rows into regs, ctx += W^T V (unnormalized).
        float vreg[64];
        #pragma unroll
        for (int jj = 0; jj < 64; ++jj)
            vreg[jj] = V[((b*L_ + k0 + jj)*H_ + h)*D_ + lane];
        #pragma unroll
        for (int j = 0; j < 12; ++j) {
            int u = wave + 4*j;
            if (u >= U_) break;
            float a0 = 0.f, a1 = 0.f, a2 = 0.f, a3 = 0.f;
            const float4* w4 = (const float4*)&wlds[u*64];
            #pragma unroll
            for (int cc = 0; cc < 16; ++cc) {
                float4 wv = w4[cc];
                a0 += wv.x*vreg[cc*4];   a1 += wv.y*vreg[cc*4+1];
                a2 += wv.z*vreg[cc*4+2]; a3 += wv.w*vreg[cc*4+3];
            }
            ctx_u[j] += (a0+a1)+(a2+a3);
        }
    }

    // write partials: per-u l (cross-lane reduce once) and unnormalized ctx
    #pragma unroll
    for (int j = 0; j < 12; ++j) {
        int u = wave + 4*j;
        if (u >= U_) break;
        float l = lpart[j];
        #pragma unroll
        for (int o = 32; o; o >>= 1) l += __shfl_xor(l, o);
        int pbase = (bh*NC_ + c)*U_ + u;
        if (lane == 0) pl[pbase] = l;
        pctx[pbase*D_ + lane] = ctx_u[j];
    }
}

// ---------------- combine NC_ partials (plain sums), scatter into output ----------------
__global__ void combine_kernel(const float* __restrict__ pl,
                               const float* __restrict__ pctx, const int* __restrict__ topq,
                               float* __restrict__ out) {
    int bh = blockIdx.x; int b = bh >> 3, h = bh & 7;
    int t = threadIdx.x;
    int lane_d = t & 63, usub = t >> 6;
    for (int u = usub; u < U_; u += 4) {
        int pb = bh*NC_*U_ + u;
        float lg = 0.f, cx = 0.f;
        for (int cc = 0; cc < NC_; ++cc) {
            lg += pl[pb + cc*U_];
            cx += pctx[(pb + cc*U_)*D_ + lane_d];
        }
        int q = topq[bh*U_ + u];
        out[((b*L_ + q)*H_ + h)*D_ + lane_d] = cx / lg;
    }
}

extern "C" void kernel_launch(void* const* d_in, const int* in_sizes, int n_in,
                              void* d_out, int out_size, void* d_ws, size_t ws_size,
                              hipStream_t stream) {
    const float* Q  = (const float*)d_in[0];
    const float* K  = (const float*)d_in[1];
    const float* V  = (const float*)d_in[2];
    const int* idx  = (const int*)d_in[3];
    float* out = (float*)d_out;
    float* ws  = (float*)d_ws;

    float* mean = ws + OFF_MEAN;
    float* mp   = ws + OFF_MP;
    float* M    = ws + OFF_M;
    int*   topq = (int*)(ws + OFF_TOPQ);
    float* pl   = ws + OFF_PL;
    float* pctx = ws + OFF_PCTX;

    mean_kernel   <<<BH_*16, 256, 0, stream>>>(V, mp);
    meanfin_kernel<<<(BH_*D_)/256, 256, 0, stream>>>(mp, mean);
    fill_kernel   <<<2048, 256, 0, stream>>>(mean, (float4*)out);
    m_kernel      <<<1024, 256, 0, stream>>>(Q, K, idx, M);
    topk_kernel   <<<BH_/4, 256, 0, stream>>>(M, topq);
    attn_kernel   <<<BH_*NC_, 256, 0, stream>>>(Q, K, V, topq, pl, pctx);
    combine_kernel<<<BH_, 256, 0, stream>>>(pl, pctx, topq, out);
}

// Round 17
// 732.502 us; speedup vs baseline: 1.4254x; 1.4254x over previous
//
#include <hip/hip_runtime.h>
#include <hip/hip_bf16.h>
#include <math.h>

#define B_ 16
#define L_ 4096
#define H_ 8
#define D_ 64
#define S_ 45          // sample_k = 5*ceil(ln(4096)) = 45
#define U_ 45          // n_top = 45
#define BH_ (B_*H_)
#define NC_ 8          // k-chunks per (b,h) in attention kernel
#define CK_ (L_/NC_)   // 512 keys per chunk

// ---- ws layout (float offsets) ----
#define OFF_MEAN 0                      // 8192
#define OFF_MP   (OFF_MEAN + BH_*D_)    // 16*8192 = 131072
#define OFF_M    (OFF_MP + 16*BH_*D_)   // 524288
#define OFF_TOPQ (OFF_M + BH_*L_)       // 5760 ints
#define OFF_PL   (OFF_TOPQ + BH_*U_ + 32)
#define OFF_PCTX (OFF_PL + BH_*NC_*U_)  // BH_*NC_*U_*D_ floats

// ---------------- mean over L of V, stage 1: per-chunk partials ----------------
__global__ void mean_kernel(const float* __restrict__ V, float* __restrict__ mp) {
    int bid = blockIdx.x;             // BH_*16
    int bh = bid >> 4, chunk = bid & 15;
    int b = bh >> 3, h = bh & 7;
    int t = threadIdx.x;              // 256
    int d = t & 63, r0 = t >> 6;      // 0..3
    float sum = 0.f;
    int base = ((b*L_ + chunk*256)*H_ + h)*D_ + d;
    for (int r = r0; r < 256; r += 4)
        sum += V[base + r*(H_*D_)];
    __shared__ float sm[256];
    sm[t] = sum; __syncthreads();
    if (t < 64) {
        float s = sm[t] + sm[t+64] + sm[t+128] + sm[t+192];
        mp[chunk*(BH_*D_) + bh*D_ + t] = s;
    }
}

// ---------------- mean stage 2 ----------------
__global__ void meanfin_kernel(const float* __restrict__ mp, float* __restrict__ mean) {
    int i = blockIdx.x*256 + threadIdx.x;   // 8192 total -> 32 blocks
    float s = 0.f;
    for (int c = 0; c < 16; ++c) s += mp[c*(BH_*D_) + i];
    mean[i] = s * (1.0f/L_);
}

// ---------------- broadcast mean into output ----------------
__global__ void fill_kernel(const float* __restrict__ mean, float4* __restrict__ out4) {
    int total = B_*L_*H_*D_/4;  // 8388608
    for (int i = blockIdx.x*blockDim.x + threadIdx.x; i < total; i += gridDim.x*blockDim.x) {
        int e = i << 2;
        int d = e & 63;
        int h = (e >> 6) & 7;
        int b = e >> 21;            // L_*H_*D_ = 2^21
        out4[i] = *(const float4*)&mean[((b<<3)+h)*D_ + d];
    }
}

// DPP-based 16-lane sum reduce: xor1, xor2 (quad_perm), half-mirror, mirror.
__device__ __forceinline__ float dpp_add16(float x) {
    int xi, yi;
    xi = __float_as_int(x);
    yi = __builtin_amdgcn_update_dpp(0, xi, 0xB1, 0xf, 0xf, true);  // quad_perm [1,0,3,2]
    x += __int_as_float(yi);
    xi = __float_as_int(x);
    yi = __builtin_amdgcn_update_dpp(0, xi, 0x4E, 0xf, 0xf, true);  // quad_perm [2,3,0,1]
    x += __int_as_float(yi);
    xi = __float_as_int(x);
    yi = __builtin_amdgcn_update_dpp(0, xi, 0x141, 0xf, 0xf, true); // row_half_mirror (^7)
    x += __int_as_float(yi);
    xi = __float_as_int(x);
    yi = __builtin_amdgcn_update_dpp(0, xi, 0x140, 0xf, 0xf, true); // row_mirror (^15)
    x += __int_as_float(yi);
    return x;
}

// dot vs q4, 16-lane reduce, accumulate max/sum
#define MRED(kv) { float p_ = q4.x*(kv).x + q4.y*(kv).y + q4.z*(kv).z + q4.w*(kv).w; \
                   p_ = dpp_add16(p_); maxv = fmaxf(maxv, p_); sumv += p_; }

// ---------------- M = max_s(QK_s) - sum_s(QK_s)/L_K ----------------
// Grid 2048 x 256: the si-loop is SPLIT (half_s = bit 3 of bid) so each block
// sweeps 8 slabs. Inner body is byte-identical to the proven VGPR-48 round-15
// body -> 8 blocks/CU = 32 waves/CU, whole grid resident, lockstep sweep.
// Each XCD sweeps 2 slabs concurrently (K+Q ~4MB = L2; L3 absorbs misses).
// ALLOCATOR LEDGER (do not touch the body): every body-shape edit re-rolled
// VGPR catastrophically (112/184/132/32-spill, rounds 6,11,12,13,16); min-waves
// launch_bounds always spills GBs (rounds 5,7,13).
// Tripwire: VGPR>80 or dur>=315us -> revert grid to 1024.
__global__ __launch_bounds__(256) void m_kernel(const float* __restrict__ Q,
                                                const float* __restrict__ K,
                                                const int* __restrict__ idx,
                                                float* __restrict__ M) {
    int bid = blockIdx.x;              // 2048
    int xcd   = bid & 7;
    int halfs = (bid >> 3) & 1;        // slab half: 0 -> slabs 0..7, 1 -> 8..15
    int slot  = bid >> 4;              // 0..127
    int q0 = slot*32;
    int t = threadIdx.x;
    int wave = t >> 6, lane = t & 63;

    __shared__ int silds[32*48];       // 6 KB, padded stride 48
    for (int g = t; g < 32*48; g += 256) {
        int u = g / 48, s = g - u*48;
        if (s < S_) silds[g] = idx[(q0+u)*S_ + s];
    }
    __syncthreads();

    int grp = lane >> 4;               // 0..3
    int d4 = (lane & 15) * 4;
    int myq = wave*4 + grp;            // 0..15

    for (int si = 0; si < 8; ++si) {
        int slab = xcd*16 + halfs*8 + si;   // == bh, 0..127
        int b = slab >> 3, h = slab & 7;
        const float* Kb = K + b*(L_*H_*D_) + h*D_;   // + k*512 + d4
        for (int half = 0; half < 2; ++half) {
            int qq = myq + half*16;    // 0..31
            int q = q0 + qq;
            const int* myidx = &silds[qq*48];
            float4 q4 = *(const float4*)&Q[(b*L_ + q)*(H_*D_) + h*D_ + d4];
            float maxv = -3.0e38f, sumv = 0.f;
            // prologue: load batch 0
            int4 ka = *(const int4*)&myidx[0];
            float4 f0 = *(const float4*)&Kb[ka.x*(H_*D_) + d4];
            float4 f1 = *(const float4*)&Kb[ka.y*(H_*D_) + d4];
            float4 f2 = *(const float4*)&Kb[ka.z*(H_*D_) + d4];
            float4 f3 = *(const float4*)&Kb[ka.w*(H_*D_) + d4];
            #pragma unroll
            for (int c2 = 0; c2 < 5; ++c2) {       // batches (2c2, 2c2+1)
                int4 kb_ = *(const int4*)&myidx[(2*c2+1)*4];
                float4 g0 = *(const float4*)&Kb[kb_.x*(H_*D_) + d4];
                float4 g1 = *(const float4*)&Kb[kb_.y*(H_*D_) + d4];
                float4 g2 = *(const float4*)&Kb[kb_.z*(H_*D_) + d4];
                float4 g3 = *(const float4*)&Kb[kb_.w*(H_*D_) + d4];
                MRED(f0); MRED(f1); MRED(f2); MRED(f3);   // batch 2c2
                int4 kc = *(const int4*)&myidx[(2*c2+2)*4];
                f0 = *(const float4*)&Kb[kc.x*(H_*D_) + d4];
                f1 = *(const float4*)&Kb[kc.y*(H_*D_) + d4];
                f2 = *(const float4*)&Kb[kc.z*(H_*D_) + d4];
                f3 = *(const float4*)&Kb[kc.w*(H_*D_) + d4];
                MRED(g0); MRED(g1); MRED(g2); MRED(g3);   // batch 2c2+1
            }
            // f holds batch 10
            MRED(f0); MRED(f1); MRED(f2); MRED(f3);
            {   // sample 44
                int k = myidx[44];
                float4 kv = *(const float4*)&Kb[k*(H_*D_) + d4];
                MRED(kv);
            }
            if ((lane & 15) == 0)
                M[slab*L_ + q] = maxv - sumv * (1.0f/L_);
        }
    }
}

// ---------------- top-45 per (b,h): one wave per bh, all in registers ----------------
__global__ __launch_bounds__(256) void topk_kernel(const float* __restrict__ M,
                                                   int* __restrict__ topq) {
    int wave = threadIdx.x >> 6, lane = threadIdx.x & 63;
    int bh = blockIdx.x*4 + wave;      // 32 blocks
    const float* Mr = M + bh*L_;
    float v[64];
    #pragma unroll
    for (int j = 0; j < 64; ++j) v[j] = Mr[j*64 + lane];
    for (int it = 0; it < U_; ++it) {
        float lm = v[0]; int lj = 0;
        #pragma unroll
        for (int j = 1; j < 64; ++j) {
            bool g = v[j] > lm;
            lm = g ? v[j] : lm;
            lj = g ? j : lj;
        }
        float bm = lm; int bi = lj*64 + lane;
        #pragma unroll
        for (int off = 1; off < 64; off <<= 1) {
            float om = __shfl_xor(bm, off);
            int   oi = __shfl_xor(bi, off);
            if (om > bm || (om == bm && oi < bi)) { bm = om; bi = oi; }
        }
        if (lane == 0) topq[bh*U_ + it] = bi;
        int wl = bi & 63, wj = bi >> 6;
        if (lane == wl) {
            #pragma unroll
            for (int j = 0; j < 64; ++j)
                if (j == wj) v[j] = -3.0e38f;
        }
    }
}

// ---------------- attention over top-45 q's, exp-direct (no online softmax) ----------------
// Unnormalized: pl = sum_k e^(s_k), pctx = sum_k e^(s_k) V[k].  exp(s) is safe:
// |s| <= |q||k|/8 << 88 for this data, so no overflow; softmax ratio is identical.
// K staging deleted (K chunk read exactly once -> global->LDS was overhead);
// kreg[8] (two D-halves) loads straight from global; waves fully independent
// after the qidx_s barrier (wlds rows wave-partitioned) -> they drift/overlap.
// Q rows via wave-uniform scalar loads (SGPR). Phase B = round-8 vreg[64] form
// (4x16 chunking spilled 3.5GB in round 9 -- do not chunk).
__global__ __launch_bounds__(256, 2) void attn_kernel(
        const float* __restrict__ Q, const float* __restrict__ K, const float* __restrict__ V,
        const int* __restrict__ topq,
        float* __restrict__ pl, float* __restrict__ pctx) {
    int bid = blockIdx.x;              // BH_*NC_
    int bh = bid / NC_, c = bid % NC_;
    int b = bh >> 3, h = bh & 7;
    int t = threadIdx.x, wave = t >> 6, lane = t & 63;

    __shared__ int   qidx_s[U_];
    __shared__ float wlds[48*64];      // 12 KB

    if (t < U_) qidx_s[t] = topq[bh*U_ + t];
    __syncthreads();

    float lpart[12], ctx_u[12];
    #pragma unroll
    for (int j = 0; j < 12; ++j) { lpart[j] = 0.f; ctx_u[j] = 0.f; }

    int k0base = c*CK_;
    for (int sc = 0; sc < CK_/64; ++sc) {      // 8 sub-chunks of 64 keys
        int k0 = k0base + sc*64;
        const float* Krow = K + ((size_t)(b*L_ + k0 + lane)*H_ + h)*D_;

        // phase A: lane = k. kreg direct from global, two D-halves; dots in dotu.
        float dotu[12];
        #pragma unroll
        for (int j = 0; j < 12; ++j) dotu[j] = 0.f;
        #pragma unroll
        for (int dh = 0; dh < 2; ++dh) {
            float4 kreg[8];
            #pragma unroll
            for (int cc = 0; cc < 8; ++cc)
                kreg[cc] = *(const float4*)&Krow[dh*32 + cc*4];
            #pragma unroll
            for (int j = 0; j < 12; ++j) {
                int u = wave + 4*j;
                if (u >= U_) break;
                int qrow = __builtin_amdgcn_readfirstlane(qidx_s[u]);
                const float* qp = Q + ((size_t)(b*L_ + qrow)*H_ + h)*D_ + dh*32;
                float d0 = 0.f, d1 = 0.f, d2 = 0.f, d3 = 0.f;
                #pragma unroll
                for (int cc = 0; cc < 8; ++cc) {
                    float4 kv = kreg[cc];
                    d0 += qp[cc*4+0]*kv.x; d1 += qp[cc*4+1]*kv.y;
                    d2 += qp[cc*4+2]*kv.z; d3 += qp[cc*4+3]*kv.w;
                }
                dotu[j] += (d0+d1)+(d2+d3);
            }
        }
        #pragma unroll
        for (int j = 0; j < 12; ++j) {
            int u = wave + 4*j;
            if (u >= U_) break;
            float e = __expf(dotu[j] * 0.125f);   // 1/sqrt(64)
            lpart[j] += e;
            wlds[u*64 + lane] = e;
        }
        // no barrier: each wave reads back only the wlds rows it wrote.

        // phase B: lane = d. V rows into regs, ctx += W^T V (unnormalized).
        float vreg[64];
        #pragma unroll
        for (int jj = 0; jj < 64; ++jj)
            vreg[jj] = V[((b*L_ + k0 + jj)*H_ + h)*D_ + lane];
        #pragma unroll
        for (int j = 0; j < 12; ++j) {
            int u = wave + 4*j;
            if (u >= U_) break;
            float a0 = 0.f, a1 = 0.f, a2 = 0.f, a3 = 0.f;
            const float4* w4 = (const float4*)&wlds[u*64];
            #pragma unroll
            for (int cc = 0; cc < 16; ++cc) {
                float4 wv = w4[cc];
                a0 += wv.x*vreg[cc*4];   a1 += wv.y*vreg[cc*4+1];
                a2 += wv.z*vreg[cc*4+2]; a3 += wv.w*vreg[cc*4+3];
            }
            ctx_u[j] += (a0+a1)+(a2+a3);
        }
    }

    // write partials: per-u l (cross-lane reduce once) and unnormalized ctx
    #pragma unroll
    for (int j = 0; j < 12; ++j) {
        int u = wave + 4*j;
        if (u >= U_) break;
        float l = lpart[j];
        #pragma unroll
        for (int o = 32; o; o >>= 1) l += __shfl_xor(l, o);
        int pbase = (bh*NC_ + c)*U_ + u;
        if (lane == 0) pl[pbase] = l;
        pctx[pbase*D_ + lane] = ctx_u[j];
    }
}

// ---------------- combine NC_ partials (plain sums), scatter into output ----------------
__global__ void combine_kernel(const float* __restrict__ pl,
                               const float* __restrict__ pctx, const int* __restrict__ topq,
                               float* __restrict__ out) {
    int bh = blockIdx.x; int b = bh >> 3, h = bh & 7;
    int t = threadIdx.x;
    int lane_d = t & 63, usub = t >> 6;
    for (int u = usub; u < U_; u += 4) {
        int pb = bh*NC_*U_ + u;
        float lg = 0.f, cx = 0.f;
        for (int cc = 0; cc < NC_; ++cc) {
            lg += pl[pb + cc*U_];
            cx += pctx[(pb + cc*U_)*D_ + lane_d];
        }
        int q = topq[bh*U_ + u];
        out[((b*L_ + q)*H_ + h)*D_ + lane_d] = cx / lg;
    }
}

extern "C" void kernel_launch(void* const* d_in, const int* in_sizes, int n_in,
                              void* d_out, int out_size, void* d_ws, size_t ws_size,
                              hipStream_t stream) {
    const float* Q  = (const float*)d_in[0];
    const float* K  = (const float*)d_in[1];
    const float* V  = (const float*)d_in[2];
    const int* idx  = (const int*)d_in[3];
    float* out = (float*)d_out;
    float* ws  = (float*)d_ws;

    float* mean = ws + OFF_MEAN;
    float* mp   = ws + OFF_MP;
    float* M    = ws + OFF_M;
    int*   topq = (int*)(ws + OFF_TOPQ);
    float* pl   = ws + OFF_PL;
    float* pctx = ws + OFF_PCTX;

    mean_kernel   <<<BH_*16, 256, 0, stream>>>(V, mp);
    meanfin_kernel<<<(BH_*D_)/256, 256, 0, stream>>>(mp, mean);
    fill_kernel   <<<2048, 256, 0, stream>>>(mean, (float4*)out);
    m_kernel      <<<2048, 256, 0, stream>>>(Q, K, idx, M);
    topk_kernel   <<<BH_/4, 256, 0, stream>>>(M, topq);
    attn_kernel   <<<BH_*NC_, 256, 0, stream>>>(Q, K, V, topq, pl, pctx);
    combine_kernel<<<BH_, 256, 0, stream>>>(pl, pctx, topq, out);
}

// Round 18
// 664.233 us; speedup vs baseline: 1.5718x; 1.1028x over previous
//
#include <hip/hip_runtime.h>
#include <hip/hip_bf16.h>
#include <math.h>

#define B_ 16
#define L_ 4096
#define H_ 8
#define D_ 64
#define S_ 45          // sample_k = 5*ceil(ln(4096)) = 45
#define U_ 45          // n_top = 45
#define BH_ (B_*H_)
#define NC_ 8          // k-chunks per (b,h) in attention kernel
#define CK_ (L_/NC_)   // 512 keys per chunk

// ---- ws layout (float offsets) ----
#define OFF_MEAN 0                      // 8192
#define OFF_MP   (OFF_MEAN + BH_*D_)    // 16*8192 = 131072
#define OFF_M    (OFF_MP + 16*BH_*D_)   // 524288
#define OFF_TOPQ (OFF_M + BH_*L_)       // 5760 ints
#define OFF_PL   (OFF_TOPQ + BH_*U_ + 32)
#define OFF_PCTX (OFF_PL + BH_*NC_*U_)  // BH_*NC_*U_*D_ floats

// ---------------- mean over L of V, stage 1: per-chunk partials ----------------
__global__ void mean_kernel(const float* __restrict__ V, float* __restrict__ mp) {
    int bid = blockIdx.x;             // BH_*16
    int bh = bid >> 4, chunk = bid & 15;
    int b = bh >> 3, h = bh & 7;
    int t = threadIdx.x;              // 256
    int d = t & 63, r0 = t >> 6;      // 0..3
    float sum = 0.f;
    int base = ((b*L_ + chunk*256)*H_ + h)*D_ + d;
    for (int r = r0; r < 256; r += 4)
        sum += V[base + r*(H_*D_)];
    __shared__ float sm[256];
    sm[t] = sum; __syncthreads();
    if (t < 64) {
        float s = sm[t] + sm[t+64] + sm[t+128] + sm[t+192];
        mp[chunk*(BH_*D_) + bh*D_ + t] = s;
    }
}

// ---------------- mean stage 2 ----------------
__global__ void meanfin_kernel(const float* __restrict__ mp, float* __restrict__ mean) {
    int i = blockIdx.x*256 + threadIdx.x;   // 8192 total -> 32 blocks
    float s = 0.f;
    for (int c = 0; c < 16; ++c) s += mp[c*(BH_*D_) + i];
    mean[i] = s * (1.0f/L_);
}

// ---------------- broadcast mean into output ----------------
__global__ void fill_kernel(const float* __restrict__ mean, float4* __restrict__ out4) {
    int total = B_*L_*H_*D_/4;  // 8388608
    for (int i = blockIdx.x*blockDim.x + threadIdx.x; i < total; i += gridDim.x*blockDim.x) {
        int e = i << 2;
        int d = e & 63;
        int h = (e >> 6) & 7;
        int b = e >> 21;            // L_*H_*D_ = 2^21
        out4[i] = *(const float4*)&mean[((b<<3)+h)*D_ + d];
    }
}

// DPP-based 16-lane sum reduce: xor1, xor2 (quad_perm), half-mirror, mirror.
__device__ __forceinline__ float dpp_add16(float x) {
    int xi, yi;
    xi = __float_as_int(x);
    yi = __builtin_amdgcn_update_dpp(0, xi, 0xB1, 0xf, 0xf, true);  // quad_perm [1,0,3,2]
    x += __int_as_float(yi);
    xi = __float_as_int(x);
    yi = __builtin_amdgcn_update_dpp(0, xi, 0x4E, 0xf, 0xf, true);  // quad_perm [2,3,0,1]
    x += __int_as_float(yi);
    xi = __float_as_int(x);
    yi = __builtin_amdgcn_update_dpp(0, xi, 0x141, 0xf, 0xf, true); // row_half_mirror (^7)
    x += __int_as_float(yi);
    xi = __float_as_int(x);
    yi = __builtin_amdgcn_update_dpp(0, xi, 0x140, 0xf, 0xf, true); // row_mirror (^15)
    x += __int_as_float(yi);
    return x;
}

// dot vs q4, 16-lane reduce, accumulate max/sum
#define MRED(kv) { float p_ = q4.x*(kv).x + q4.y*(kv).y + q4.z*(kv).z + q4.w*(kv).w; \
                   p_ = dpp_add16(p_); maxv = fmaxf(maxv, p_); sumv += p_; }

// ---------------- M = max_s(QK_s) - sum_s(QK_s)/L_K ----------------
// ROUND-15 OPTIMUM -- FROZEN. Grid 1024 x 256, plain launch_bounds(256):
// VGPR 48 -> 4 blocks/CU grid-capped, whole grid resident, single lockstep
// K sweep. Slab = (b, single head): K 1MB + Q-window 1MB < 4MB L2.
// DESIGN-SPACE MAP (rounds 5-17, all worse): min-waves launch_bounds ->
// VGPR collapse + GB-scale spill (r5,7,13); body flatten/interleave/8-lane ->
// VGPR 112/184/132 occupancy loss (r6,11,12,16); split-sweep grid 2048 ->
// VGPR 68 > 64-reg cliff + 2-slab L2 thrash (r17). This pocket is the floor.
__global__ __launch_bounds__(256) void m_kernel(const float* __restrict__ Q,
                                                const float* __restrict__ K,
                                                const int* __restrict__ idx,
                                                float* __restrict__ M) {
    int bid = blockIdx.x;              // 1024
    int xcd  = bid & 7;
    int slot = bid >> 3;               // 0..127
    int q0 = slot*32;
    int t = threadIdx.x;
    int wave = t >> 6, lane = t & 63;

    __shared__ int silds[32*48];       // 6 KB, padded stride 48
    for (int g = t; g < 32*48; g += 256) {
        int u = g / 48, s = g - u*48;
        if (s < S_) silds[g] = idx[(q0+u)*S_ + s];
    }
    __syncthreads();

    int grp = lane >> 4;               // 0..3
    int d4 = (lane & 15) * 4;
    int myq = wave*4 + grp;            // 0..15

    for (int si = 0; si < 16; ++si) {
        int slab = xcd*16 + si;        // == bh, 0..127
        int b = slab >> 3, h = slab & 7;
        const float* Kb = K + b*(L_*H_*D_) + h*D_;   // + k*512 + d4
        for (int half = 0; half < 2; ++half) {
            int qq = myq + half*16;    // 0..31
            int q = q0 + qq;
            const int* myidx = &silds[qq*48];
            float4 q4 = *(const float4*)&Q[(b*L_ + q)*(H_*D_) + h*D_ + d4];
            float maxv = -3.0e38f, sumv = 0.f;
            // prologue: load batch 0
            int4 ka = *(const int4*)&myidx[0];
            float4 f0 = *(const float4*)&Kb[ka.x*(H_*D_) + d4];
            float4 f1 = *(const float4*)&Kb[ka.y*(H_*D_) + d4];
            float4 f2 = *(const float4*)&Kb[ka.z*(H_*D_) + d4];
            float4 f3 = *(const float4*)&Kb[ka.w*(H_*D_) + d4];
            #pragma unroll
            for (int c2 = 0; c2 < 5; ++c2) {       // batches (2c2, 2c2+1)
                int4 kb_ = *(const int4*)&myidx[(2*c2+1)*4];
                float4 g0 = *(const float4*)&Kb[kb_.x*(H_*D_) + d4];
                float4 g1 = *(const float4*)&Kb[kb_.y*(H_*D_) + d4];
                float4 g2 = *(const float4*)&Kb[kb_.z*(H_*D_) + d4];
                float4 g3 = *(const float4*)&Kb[kb_.w*(H_*D_) + d4];
                MRED(f0); MRED(f1); MRED(f2); MRED(f3);   // batch 2c2
                int4 kc = *(const int4*)&myidx[(2*c2+2)*4];
                f0 = *(const float4*)&Kb[kc.x*(H_*D_) + d4];
                f1 = *(const float4*)&Kb[kc.y*(H_*D_) + d4];
                f2 = *(const float4*)&Kb[kc.z*(H_*D_) + d4];
                f3 = *(const float4*)&Kb[kc.w*(H_*D_) + d4];
                MRED(g0); MRED(g1); MRED(g2); MRED(g3);   // batch 2c2+1
            }
            // f holds batch 10
            MRED(f0); MRED(f1); MRED(f2); MRED(f3);
            {   // sample 44
                int k = myidx[44];
                float4 kv = *(const float4*)&Kb[k*(H_*D_) + d4];
                MRED(kv);
            }
            if ((lane & 15) == 0)
                M[slab*L_ + q] = maxv - sumv * (1.0f/L_);
        }
    }
}

// ---------------- top-45 per (b,h): one wave per bh, all in registers ----------------
__global__ __launch_bounds__(256) void topk_kernel(const float* __restrict__ M,
                                                   int* __restrict__ topq) {
    int wave = threadIdx.x >> 6, lane = threadIdx.x & 63;
    int bh = blockIdx.x*4 + wave;      // 32 blocks
    const float* Mr = M + bh*L_;
    float v[64];
    #pragma unroll
    for (int j = 0; j < 64; ++j) v[j] = Mr[j*64 + lane];
    for (int it = 0; it < U_; ++it) {
        float lm = v[0]; int lj = 0;
        #pragma unroll
        for (int j = 1; j < 64; ++j) {
            bool g = v[j] > lm;
            lm = g ? v[j] : lm;
            lj = g ? j : lj;
        }
        float bm = lm; int bi = lj*64 + lane;
        #pragma unroll
        for (int off = 1; off < 64; off <<= 1) {
            float om = __shfl_xor(bm, off);
            int   oi = __shfl_xor(bi, off);
            if (om > bm || (om == bm && oi < bi)) { bm = om; bi = oi; }
        }
        if (lane == 0) topq[bh*U_ + it] = bi;
        int wl = bi & 63, wj = bi >> 6;
        if (lane == wl) {
            #pragma unroll
            for (int j = 0; j < 64; ++j)
                if (j == wj) v[j] = -3.0e38f;
        }
    }
}

// ---------------- attention over top-45 q's, exp-direct (no online softmax) ----------------
// Unnormalized: pl = sum_k e^(s_k), pctx = sum_k e^(s_k) V[k].  exp(s) is safe:
// |s| <= |q||k|/8 << 88 for this data, so no overflow; softmax ratio is identical.
// K staging deleted (K chunk read exactly once -> global->LDS was overhead);
// kreg[8] (two D-halves) loads straight from global; waves fully independent
// after the qidx_s barrier (wlds rows wave-partitioned) -> they drift/overlap.
// Q rows via wave-uniform scalar loads (SGPR). Phase B = round-8 vreg[64] form
// (4x16 chunking spilled 3.5GB in round 9 -- do not chunk).
__global__ __launch_bounds__(256, 2) void attn_kernel(
        const float* __restrict__ Q, const float* __restrict__ K, const float* __restrict__ V,
        const int* __restrict__ topq,
        float* __restrict__ pl, float* __restrict__ pctx) {
    int bid = blockIdx.x;              // BH_*NC_
    int bh = bid / NC_, c = bid % NC_;
    int b = bh >> 3, h = bh & 7;
    int t = threadIdx.x, wave = t >> 6, lane = t & 63;

    __shared__ int   qidx_s[U_];
    __shared__ float wlds[48*64];      // 12 KB

    if (t < U_) qidx_s[t] = topq[bh*U_ + t];
    __syncthreads();

    float lpart[12], ctx_u[12];
    #pragma unroll
    for (int j = 0; j < 12; ++j) { lpart[j] = 0.f; ctx_u[j] = 0.f; }

    int k0base = c*CK_;
    for (int sc = 0; sc < CK_/64; ++sc) {      // 8 sub-chunks of 64 keys
        int k0 = k0base + sc*64;
        const float* Krow = K + ((size_t)(b*L_ + k0 + lane)*H_ + h)*D_;

        // phase A: lane = k. kreg direct from global, two D-halves; dots in dotu.
        float dotu[12];
        #pragma unroll
        for (int j = 0; j < 12; ++j) dotu[j] = 0.f;
        #pragma unroll
        for (int dh = 0; dh < 2; ++dh) {
            float4 kreg[8];
            #pragma unroll
            for (int cc = 0; cc < 8; ++cc)
                kreg[cc] = *(const float4*)&Krow[dh*32 + cc*4];
            #pragma unroll
            for (int j = 0; j < 12; ++j) {
                int u = wave + 4*j;
                if (u >= U_) break;
                int qrow = __builtin_amdgcn_readfirstlane(qidx_s[u]);
                const float* qp = Q + ((size_t)(b*L_ + qrow)*H_ + h)*D_ + dh*32;
                float d0 = 0.f, d1 = 0.f, d2 = 0.f, d3 = 0.f;
                #pragma unroll
                for (int cc = 0; cc < 8; ++cc) {
                    float4 kv = kreg[cc];
                    d0 += qp[cc*4+0]*kv.x; d1 += qp[cc*4+1]*kv.y;
                    d2 += qp[cc*4+2]*kv.z; d3 += qp[cc*4+3]*kv.w;
                }
                dotu[j] += (d0+d1)+(d2+d3);
            }
        }
        #pragma unroll
        for (int j = 0; j < 12; ++j) {
            int u = wave + 4*j;
            if (u >= U_) break;
            float e = __expf(dotu[j] * 0.125f);   // 1/sqrt(64)
            lpart[j] += e;
            wlds[u*64 + lane] = e;
        }
        // no barrier: each wave reads back only the wlds rows it wrote.

        // phase B: lane = d. V rows into regs, ctx += W^T V (unnormalized).
        float vreg[64];
        #pragma unroll
        for (int jj = 0; jj < 64; ++jj)
            vreg[jj] = V[((b*L_ + k0 + jj)*H_ + h)*D_ + lane];
        #pragma unroll
        for (int j = 0; j < 12; ++j) {
            int u = wave + 4*j;
            if (u >= U_) break;
            float a0 = 0.f, a1 = 0.f, a2 = 0.f, a3 = 0.f;
            const float4* w4 = (const float4*)&wlds[u*64];
            #pragma unroll
            for (int cc = 0; cc < 16; ++cc) {
                float4 wv = w4[cc];
                a0 += wv.x*vreg[cc*4];   a1 += wv.y*vreg[cc*4+1];
                a2 += wv.z*vreg[cc*4+2]; a3 += wv.w*vreg[cc*4+3];
            }
            ctx_u[j] += (a0+a1)+(a2+a3);
        }
    }

    // write partials: per-u l (cross-lane reduce once) and unnormalized ctx
    #pragma unroll
    for (int j = 0; j < 12; ++j) {
        int u = wave + 4*j;
        if (u >= U_) break;
        float l = lpart[j];
        #pragma unroll
        for (int o = 32; o; o >>= 1) l += __shfl_xor(l, o);
        int pbase = (bh*NC_ + c)*U_ + u;
        if (lane == 0) pl[pbase] = l;
        pctx[pbase*D_ + lane] = ctx_u[j];
    }
}

// ---------------- combine NC_ partials (plain sums), scatter into output ----------------
__global__ void combine_kernel(const float* __restrict__ pl,
                               const float* __restrict__ pctx, const int* __restrict__ topq,
                               float* __restrict__ out) {
    int bh = blockIdx.x; int b = bh >> 3, h = bh & 7;
    int t = threadIdx.x;
    int lane_d = t & 63, usub = t >> 6;
    for (int u = usub; u < U_; u += 4) {
        int pb = bh*NC_*U_ + u;
        float lg = 0.f, cx = 0.f;
        for (int cc = 0; cc < NC_; ++cc) {
            lg += pl[pb + cc*U_];
            cx += pctx[(pb + cc*U_)*D_ + lane_d];
        }
        int q = topq[bh*U_ + u];
        out[((b*L_ + q)*H_ + h)*D_ + lane_d] = cx / lg;
    }
}

extern "C" void kernel_launch(void* const* d_in, const int* in_sizes, int n_in,
                              void* d_out, int out_size, void* d_ws, size_t ws_size,
                              hipStream_t stream) {
    const float* Q  = (const float*)d_in[0];
    const float* K  = (const float*)d_in[1];
    const float* V  = (const float*)d_in[2];
    const int* idx  = (const int*)d_in[3];
    float* out = (float*)d_out;
    float* ws  = (float*)d_ws;

    float* mean = ws + OFF_MEAN;
    float* mp   = ws + OFF_MP;
    float* M    = ws + OFF_M;
    int*   topq = (int*)(ws + OFF_TOPQ);
    float* pl   = ws + OFF_PL;
    float* pctx = ws + OFF_PCTX;

    mean_kernel   <<<BH_*16, 256, 0, stream>>>(V, mp);
    meanfin_kernel<<<(BH_*D_)/256, 256, 0, stream>>>(mp, mean);
    fill_kernel   <<<2048, 256, 0, stream>>>(mean, (float4*)out);
    m_kernel      <<<1024, 256, 0, stream>>>(Q, K, idx, M);
    topk_kernel   <<<BH_/4, 256, 0, stream>>>(M, topq);
    attn_kernel   <<<BH_*NC_, 256, 0, stream>>>(Q, K, V, topq, pl, pctx);
    combine_kernel<<<BH_, 256, 0, stream>>>(pl, pctx, topq, out);
}